// Round 1
// baseline (200.486 us; speedup 1.0000x reference)
//
#include <hip/hip_runtime.h>

typedef short bf16x8 __attribute__((ext_vector_type(8)));
typedef float f32x4 __attribute__((ext_vector_type(4)));

#define MFMA16(a, b, c) __builtin_amdgcn_mfma_f32_16x16x32_bf16(a, b, c, 0, 0, 0)

constexpr int Bn = 4, Sn = 4096, En = 1024, Hn = 128;
constexpr float CSCALE = 1.44269504089f * 0.03125f;   // log2(e) * E^-0.5

// attn partials: qt64 uses ceil((qt64+1)/16) chunks; slot base = prefix sum
__device__ inline int sb64(int qt) {
    int a = qt >> 4, r = qt & 15;
    return 8 * a * (a + 1) + r * (a + 1);
}
constexpr int SB = 160;            // sb64(64)
constexpr int SLOT_F = 8320;       // 64*128 O + 64 m + 64 l floats
constexpr int NITEMS = 640;        // 160 (qt,ch) chunks x 4 batches

__device__ inline unsigned short f2bf(float f) {
    unsigned int u = __builtin_bit_cast(unsigned int, f);
    u += 0x7fff + ((u >> 16) & 1);
    return (unsigned short)(u >> 16);
}

__device__ inline unsigned int pk2(float a, float b) {
    unsigned int ua = __builtin_bit_cast(unsigned int, a) + 0x8000u;
    unsigned int ub = __builtin_bit_cast(unsigned int, b) + 0x8000u;
    return __builtin_amdgcn_perm(ub, ua, 0x07060302u);
}

__device__ inline void gld16(const unsigned short* g, unsigned short* l) {
    __builtin_amdgcn_global_load_lds((const __attribute__((address_space(1))) void*)g,
                                     (__attribute__((address_space(3))) void*)l, 16, 0, 0);
}

// ---------------- prep: W fp32 -> bf16, [q,k,v][h][E]; block 0 also builds the
// attn work queue (counter + 640 items sorted longest-chunk-first) ----------------
__global__ __launch_bounds__(256) void prep_kernel(
    const float* __restrict__ Wk, const float* __restrict__ Wq, const float* __restrict__ Wv,
    unsigned short* __restrict__ wb, unsigned int* __restrict__ queue)
{
    int gy = blockIdx.x >> 5;
    const float* src = (gy == 0) ? Wq : (gy == 1) ? Wk : Wv;
    unsigned short* dst = wb + (size_t)gy * Hn * En;
    int t = (blockIdx.x & 31) * 256 + threadIdx.x;
    const float4* s4 = (const float4*)src;
    for (int i = 0; i < 4; ++i) {
        float4 v = s4[(size_t)t * 4 + i];
        uint2 w2 = { pk2(v.x, v.y), pk2(v.z, v.w) };
        *(uint2*)&dst[(size_t)t * 16 + i * 4] = w2;
    }
    if (blockIdx.x == 0) {
        if (threadIdx.x == 0) queue[0] = 0u;        // work counter, reset every launch
        // thread tid -> candidate chunk (qt = tid>>2, ch = tid&3); valid iff ch < nch
        int qt = threadIdx.x >> 2, ch = threadIdx.x & 3;
        int nch = (qt + 16) >> 4;                   // ceil((qt+1)/16)
        if (ch < nch) {
            int nloc = min(16, qt + 1 - ch * 16);
            int key = (nloc << 6) | qt;             // sort: nloc desc, then qt desc
            int rank = 0;
            for (int p = 0; p < 256; ++p) {
                int q2 = p >> 2, c2 = p & 3;
                int n2 = (q2 + 16) >> 4;
                if (c2 < n2) {
                    int nl2 = min(16, q2 + 1 - c2 * 16);
                    int k2 = (nl2 << 6) | q2;
                    if (k2 > key || (k2 == key && p < threadIdx.x)) ++rank;
                }
            }
            for (int b = 0; b < 4; ++b)             // batch innermost: 4 copies adjacent
                queue[1 + rank * 4 + b] = (unsigned int)(qt | (ch << 6) | (b << 8));
        }
    }
}

// ---------------- QKV projection (R7 structure — async bf16 W staging) ----------------
__global__ __launch_bounds__(256, 3) void proj_kernel(
    const float* __restrict__ x, const unsigned short* __restrict__ wb,
    unsigned short* __restrict__ qb, unsigned short* __restrict__ kb,
    unsigned short* __restrict__ vbT)
{
    __shared__ __align__(16) unsigned short xs[2][64][64];
    __shared__ __align__(16) unsigned short wsm[2][128][64];

    const int gy = blockIdx.y;
    const unsigned short* wg = wb + (size_t)gy * Hn * En;

    const int m0 = blockIdx.x * 64;
    const int tid = threadIdx.x;
    const int lane = tid & 63, wave = tid >> 6;
    const int l15 = lane & 15, quad = lane >> 4;
    const int wm = (wave & 1) * 32;
    const int wn = (wave >> 1) * 64;

    f32x4 acc[2][4] = {};
    float4 xp[4];

    auto loadx = [&](int kc) {
        for (int p4 = 0; p4 < 4; ++p4) {
            int i = p4 * 256 + tid, row = i >> 4, c4 = (i & 15) * 4;
            xp[p4] = *(const float4*)&x[(size_t)(m0 + row) * En + kc * 64 + c4];
        }
    };
    auto writex = [&](int c) {
        for (int p4 = 0; p4 < 4; ++p4) {
            int i = p4 * 256 + tid, row = i >> 4, hc = i & 15;
            uint2 w2 = { pk2(xp[p4].x, xp[p4].y), pk2(xp[p4].z, xp[p4].w) };
            *(uint2*)((char*)&xs[c][0][0] + row * 128 + (((hc >> 1) ^ (row & 7)) << 4) + ((hc & 1) << 3)) = w2;
        }
    };
    auto issueW = [&](int kc, int c) {
        for (int j = 0; j < 4; ++j) {
            int seg = (wave * 4 + j) * 1024;
            int d = seg + (lane << 4);
            int row = d >> 7, chp = (d >> 4) & 7;
            gld16(wg + (size_t)row * En + kc * 64 + ((chp ^ (row & 7)) << 3),
                  (unsigned short*)((char*)&wsm[c][0][0] + seg));
        }
    };

    loadx(0);
    issueW(0, 0);
    writex(0);
    loadx(1);

    for (int kc = 0; kc < En / 64; ++kc) {
        const int c = kc & 1;
        __syncthreads();
        if (kc + 1 < En / 64) {
            issueW(kc + 1, c ^ 1);
            writex(c ^ 1);
            int kn = (kc + 2 < En / 64) ? kc + 2 : En / 64 - 1;
            loadx(kn);
        }
        bf16x8 xf[2][2], wf[4][2];
        for (int i = 0; i < 2; ++i)
            for (int kk = 0; kk < 2; ++kk) {
                int row = wm + i * 16 + l15;
                int chn = (kk * 4 + quad) ^ (row & 7);
                xf[i][kk] = *(const bf16x8*)((char*)&xs[c][0][0] + row * 128 + (chn << 4));
            }
        for (int j = 0; j < 4; ++j)
            for (int kk = 0; kk < 2; ++kk) {
                int row = wn + j * 16 + l15;
                int chn = (kk * 4 + quad) ^ (row & 7);
                wf[j][kk] = *(const bf16x8*)((char*)&wsm[c][0][0] + row * 128 + (chn << 4));
            }
        if (gy != 2) {
            for (int kk = 0; kk < 2; ++kk)
                for (int i = 0; i < 2; ++i)
                    for (int j = 0; j < 4; ++j)
                        acc[i][j] = MFMA16(xf[i][kk], wf[j][kk], acc[i][j]);
        } else {
            for (int kk = 0; kk < 2; ++kk)
                for (int i = 0; i < 2; ++i)
                    for (int j = 0; j < 4; ++j)
                        acc[i][j] = MFMA16(wf[j][kk], xf[i][kk], acc[i][j]);
        }
    }

    if (gy != 2) {
        unsigned short* ob = (gy == 0) ? qb : kb;
        const float osc = (gy == 0) ? CSCALE : 1.0f;
        for (int i = 0; i < 2; ++i) {
            int rowb = m0 + wm + i * 16 + quad * 4;
            for (int j = 0; j < 4; ++j) {
                int col = wn + j * 16 + l15;
                for (int r = 0; r < 4; ++r)
                    ob[(size_t)(rowb + r) * Hn + col] = f2bf(acc[i][j][r] * osc);
            }
        }
    } else {
        for (int j = 0; j < 4; ++j) {
            int hb = wn + j * 16 + quad * 4;
            for (int i = 0; i < 2; ++i) {
                int sp = m0 + wm + i * 16 + l15;
                int bb = sp >> 12, ss = sp & 4095;
                for (int r = 0; r < 4; ++r)
                    vbT[((size_t)(bb * 128 + hb + r)) * Sn + ss] = f2bf(acc[i][j][r]);
            }
        }
    }
}

// ---------------- attention: persistent blocks + dynamic work queue ----------------
// grid = 768 blocks (3/CU residency), 256 thr = 4 waves; each block loops pulling
// (qt,ch,b) chunk items (sorted longest-first) from an atomic counter. This fixes
// the static-grid imbalance where all 4 batch copies of the heaviest chunks piled
// onto the same CUs (measured 16.7% avg occupancy vs 37.5% cap).
// Chunk = up to 16 BK=64 k-tiles. All waves share one K/V LDS tile (fetch-efficient).
// Per-lane online softmax (S^T = K Q^T: q on lane&15). Partials to ws when nch>1.
__global__ __launch_bounds__(256, 3) void attn_kernel(
    const unsigned short* __restrict__ qb, const unsigned short* __restrict__ kb,
    const unsigned short* __restrict__ vbT, float* __restrict__ out,
    float* __restrict__ part, unsigned int* __restrict__ queue)
{
    __shared__ unsigned short ks[64][132];    // K tile [key][h]
    __shared__ unsigned short vt[128][68];    // V^T [h][key]
    __shared__ unsigned short ps[4][16][72];  // per-wave P strip [q][key]
    __shared__ unsigned int sh_item;

    const int tid = threadIdx.x;
    const int lane = tid & 63, wave = tid >> 6;
    const int l15 = lane & 15, quad = lane >> 4;
    unsigned short* psrow = &ps[wave][l15][0];

    for (;;) {
        if (tid == 0) sh_item = atomicAdd(queue, 1u);
        __syncthreads();                       // also fences ks/vt reuse across items
        const unsigned int it = sh_item;
        if (it >= (unsigned int)NITEMS) return;
        const unsigned int wi = queue[1 + it];
        const int qt = (int)(wi & 63u);
        const int ch = (int)((wi >> 6) & 3u);
        const int b  = (int)((wi >> 8) & 3u);
        const int T  = qt + 1;                 // total k-tiles for this q-tile
        const int nch = (T + 15) >> 4;
        const int t0 = ch * 16;
        const int nloc = min(16, T - t0);
        const int q0 = qt * 64;

        const unsigned short* qg = qb + (size_t)(b * Sn + q0) * Hn;
        bf16x8 qf[4];
        for (int f = 0; f < 4; ++f)
            qf[f] = *(const bf16x8*)&qg[(wave * 16 + l15) * Hn + f * 32 + quad * 8];

        f32x4 o[8] = {};             // O^T: h = t*16+quad*4+r, q = l15 (this wave's row group)
        float m_r = -INFINITY, l_r = 0.f;

        const unsigned short* kg = kb + (size_t)b * Sn * Hn;
        const unsigned short* vg = vbT + (size_t)b * 128 * Sn;

        bf16x8 kreg[4], vreg[4];
        auto loadKV = [&](int gt) {
            int kt0 = gt * 64;
            for (int p4 = 0; p4 < 4; ++p4) {
                int i = p4 * 256 + tid;
                kreg[p4] = *(const bf16x8*)&kg[(size_t)(kt0 + (i >> 4)) * Hn + (i & 15) * 8];
                vreg[p4] = *(const bf16x8*)&vg[(size_t)(i >> 3) * Sn + kt0 + (i & 7) * 8];
            }
        };

        loadKV(t0);
        for (int tl = 0; tl < nloc; ++tl) {
            const int gt = t0 + tl;
            for (int p4 = 0; p4 < 4; ++p4) {
                int i = p4 * 256 + tid;
                *(bf16x8*)&ks[i >> 4][(i & 15) * 8] = kreg[p4];
                *(bf16x8*)&vt[i >> 3][(i & 7) * 8] = vreg[p4];
            }
            __syncthreads();
            if (tl + 1 < nloc) loadKV(gt + 1);

            // S^T: A = K (m=key), B = Q (n=q). u[nt][r]: key = gt*64+nt*16+quad*4+r, q = l15
            float u[4][4];
            for (int nt = 0; nt < 4; ++nt) {
                f32x4 s = {};
                for (int kk = 0; kk < 4; ++kk) {
                    bf16x8 kf = *(const bf16x8*)&ks[nt * 16 + l15][kk * 32 + quad * 8];
                    s = MFMA16(kf, qf[kk], s);
                }
                for (int r = 0; r < 4; ++r) u[nt][r] = s[r];
            }
            if (gt == qt) {   // only the last tile intersects the diagonal
                int qq = wave * 16 + l15;
                for (int nt = 0; nt < 4; ++nt)
                    for (int r = 0; r < 4; ++r)
                        if (nt * 16 + quad * 4 + r > qq) u[nt][r] = -INFINITY;
            }
            // per-lane online softmax (log2 domain; CSCALE folded into q at projection)
            float mx = -INFINITY;
            for (int nt = 0; nt < 4; ++nt)
                for (int r = 0; r < 4; ++r) mx = fmaxf(mx, u[nt][r]);
            mx = fmaxf(mx, __shfl_xor(mx, 16));
            mx = fmaxf(mx, __shfl_xor(mx, 32));
            float mn = fmaxf(m_r, mx);
            float alpha = exp2f(m_r - mn);
            m_r = mn;
            float sum = 0.f;
            for (int nt = 0; nt < 4; ++nt)
                for (int r = 0; r < 4; ++r) {
                    float pv = exp2f(u[nt][r] - mn);
                    u[nt][r] = pv;
                    sum += pv;
                }
            sum += __shfl_xor(sum, 16);
            sum += __shfl_xor(sum, 32);
            l_r = l_r * alpha + sum;

            // P -> LDS [q][key] (same-wave strip; no barrier needed)
            for (int nt = 0; nt < 4; ++nt) {
                uint2 w2 = { pk2(u[nt][0], u[nt][1]), pk2(u[nt][2], u[nt][3]) };
                *(uint2*)&psrow[nt * 16 + quad * 4] = w2;
            }
            for (int t = 0; t < 8; ++t) o[t] *= alpha;

            // O^T += V^T P^T
            for (int k2 = 0; k2 < 2; ++k2) {
                bf16x8 pf = *(const bf16x8*)&psrow[k2 * 32 + quad * 8];
                for (int t = 0; t < 8; ++t) {
                    bf16x8 vf = *(const bf16x8*)&vt[t * 16 + l15][k2 * 32 + quad * 8];
                    o[t] = MFMA16(vf, pf, o[t]);
                }
            }
            __syncthreads();   // protect ks/vt before next iteration's writes
        }

        if (nch == 1) {
            float inv = 1.0f / l_r;
            float* og = out + (size_t)(b * Sn + q0 + wave * 16 + l15) * Hn;
            for (int t = 0; t < 8; ++t) {
                float4 st = { o[t][0] * inv, o[t][1] * inv, o[t][2] * inv, o[t][3] * inv };
                *(float4*)&og[t * 16 + quad * 4] = st;
            }
        } else {
            float* P = part + (size_t)(b * SB + sb64(qt) + ch) * SLOT_F;
            int q = wave * 16 + l15;
            for (int t = 0; t < 8; ++t) {
                float4 st = { o[t][0], o[t][1], o[t][2], o[t][3] };
                *(float4*)&P[q * 128 + t * 16 + quad * 4] = st;
            }
            if (quad == 0) {
                P[8192 + q] = m_r;
                P[8256 + q] = l_r;
            }
        }
    }
}

// ---------------- merge partials for qt >= 16 ----------------
// grid (48, B), 256 thr: q = tid>>2 (64 rows), h0 = (tid&3)*32 (32 h each)
__global__ __launch_bounds__(256) void merge_kernel(
    const float* __restrict__ part, float* __restrict__ out)
{
    const int qt = 16 + blockIdx.x;
    const int b = blockIdx.y;
    const int nch = (qt + 16) >> 4;
    const float* P0 = part + (size_t)(b * SB + sb64(qt)) * SLOT_F;
    const int q = threadIdx.x >> 2;
    const int h0 = (threadIdx.x & 3) * 32;

    float m[4], w[4];
    float M = -INFINITY;
    for (int c = 0; c < nch; ++c) {
        m[c] = P0[(size_t)c * SLOT_F + 8192 + q];
        M = fmaxf(M, m[c]);
    }
    float L = 0.f;
    for (int c = 0; c < nch; ++c) {
        w[c] = exp2f(m[c] - M);
        L += w[c] * P0[(size_t)c * SLOT_F + 8256 + q];
    }
    float inv = 1.0f / L;

    float acc[32] = {};
    for (int c = 0; c < nch; ++c) {
        const float* Pq = P0 + (size_t)c * SLOT_F + q * 128 + h0;
        for (int j = 0; j < 8; ++j) {
            float4 v = *(const float4*)&Pq[j * 4];
            acc[j * 4 + 0] += w[c] * v.x;
            acc[j * 4 + 1] += w[c] * v.y;
            acc[j * 4 + 2] += w[c] * v.z;
            acc[j * 4 + 3] += w[c] * v.w;
        }
    }
    float* og = out + (size_t)(b * Sn + qt * 64 + q) * Hn + h0;
    for (int j = 0; j < 8; ++j) {
        float4 st = { acc[j * 4 + 0] * inv, acc[j * 4 + 1] * inv,
                      acc[j * 4 + 2] * inv, acc[j * 4 + 3] * inv };
        *(float4*)&og[j * 4] = st;
    }
}

extern "C" void kernel_launch(void* const* d_in, const int* in_sizes, int n_in,
                              void* d_out, int out_size, void* d_ws, size_t ws_size,
                              hipStream_t stream)
{
    const float* x  = (const float*)d_in[0];
    const float* Wk = (const float*)d_in[1];
    const float* Wq = (const float*)d_in[2];
    const float* Wv = (const float*)d_in[3];
    float* out = (float*)d_out;

    unsigned short* qbuf  = (unsigned short*)d_ws;                  // 4 MB (pre-scaled)
    unsigned short* kbuf  = qbuf + (size_t)Bn * Sn * Hn;            // 4 MB
    unsigned short* vbufT = kbuf + (size_t)Bn * Sn * Hn;            // 4 MB, [b][h][s]
    unsigned short* wb    = vbufT + (size_t)Bn * Sn * Hn;           // 0.75 MB bf16 W
    float* part = (float*)(wb + (size_t)3 * Hn * En);               // 21.3 MB partials
    // work queue lives in part's b=0/qt<16 slot region (only written for qt>=16,
    // byte offset >= 16*SLOT_F*4 = 532 KB) — counter at [0], 640 items at [1..641)
    unsigned int* queue = (unsigned int*)part;

    prep_kernel<<<96, 256, 0, stream>>>(Wk, Wq, Wv, wb, queue);
    proj_kernel<<<dim3(Bn * Sn / 64, 3), 256, 0, stream>>>(x, wb, qbuf, kbuf, vbufT);
    attn_kernel<<<768, 256, 0, stream>>>(qbuf, kbuf, vbufT, out, part, queue);
    merge_kernel<<<dim3(48, Bn), 256, 0, stream>>>(part, out);
}

// Round 3
// 174.404 us; speedup vs baseline: 1.1495x; 1.1495x over previous
//
#include <hip/hip_runtime.h>

typedef short bf16x8 __attribute__((ext_vector_type(8)));
typedef float f32x4 __attribute__((ext_vector_type(4)));

#define MFMA16(a, b, c) __builtin_amdgcn_mfma_f32_16x16x32_bf16(a, b, c, 0, 0, 0)

constexpr int Bn = 4, Sn = 4096, En = 1024, Hn = 128;
constexpr float CSCALE = 1.44269504089f * 0.03125f;   // log2(e) * E^-0.5

// attn partials: qt64 uses ceil((qt64+1)/16) chunks; slot base = prefix sum
__device__ inline int sb64(int qt) {
    int a = qt >> 4, r = qt & 15;
    return 8 * a * (a + 1) + r * (a + 1);
}
constexpr int SB = 160;            // sb64(64)
constexpr int SLOT_F = 8320;       // 64*128 O + 64 m + 64 l floats

__device__ inline unsigned short f2bf(float f) {
    unsigned int u = __builtin_bit_cast(unsigned int, f);
    u += 0x7fff + ((u >> 16) & 1);
    return (unsigned short)(u >> 16);
}

__device__ inline unsigned int pk2(float a, float b) {
    unsigned int ua = __builtin_bit_cast(unsigned int, a) + 0x8000u;
    unsigned int ub = __builtin_bit_cast(unsigned int, b) + 0x8000u;
    return __builtin_amdgcn_perm(ub, ua, 0x07060302u);
}

__device__ inline void gld16(const unsigned short* g, unsigned short* l) {
    __builtin_amdgcn_global_load_lds((const __attribute__((address_space(1))) void*)g,
                                     (__attribute__((address_space(3))) void*)l, 16, 0, 0);
}

// ---------------- prep: W fp32 -> bf16, [q,k,v][h][E]; block 0 also builds the
// static balanced attn schedule table (1024 slots; no atomics at run time).
// Work items: 400 full 16-tile chunks + 16 each of len 1..15 (8320 tiles total).
// Bin = CU = slot&255 (blocks L, L+256, L+512 land on the same CU under both
// linear round-robin and XCD-modular dispatch). Bin contents:
//   bins 0..127  : {full, full}            = 32 tiles
//   bins 128..239: {full, rem v, rem 17-v} = 33 tiles  (v = 2 + t/16)
//   bins 240..255: {full, full, rem 1}     = 33 tiles
// All real items in z=0..2 (768 blocks = exact 3/CU residency); z=3 = noop.
__global__ __launch_bounds__(256) void prep_kernel(
    const float* __restrict__ Wk, const float* __restrict__ Wq, const float* __restrict__ Wv,
    unsigned short* __restrict__ wb, unsigned int* __restrict__ sched)
{
    int gy = blockIdx.x >> 5;
    const float* src = (gy == 0) ? Wq : (gy == 1) ? Wk : Wv;
    unsigned short* dst = wb + (size_t)gy * Hn * En;
    int t = (blockIdx.x & 31) * 256 + threadIdx.x;
    const float4* s4 = (const float4*)src;
    for (int i = 0; i < 4; ++i) {
        float4 v = s4[(size_t)t * 4 + i];
        uint2 w2 = { pk2(v.x, v.y), pk2(v.z, v.w) };
        *(uint2*)&dst[(size_t)t * 16 + i * 4] = w2;
    }
    if (blockIdx.x == 0) {
        const int bin = threadIdx.x;
        unsigned int it[4] = { 0xFFFFu, 0xFFFFu, 0xFFFFu, 0xFFFFu };
        // full item k in [0,400): b = k/100, j = k%100 -> (qt, ch) by walking qt desc
        auto fullItem = [](int k) -> unsigned int {
            int b = k / 100, j = k - 100 * b;
            int qt = 63, ch = 0;
            for (int q = 63; q >= 0; --q) {
                int f = (q + 1) >> 4;                  // full chunks for this qt
                if (j < f) { qt = q; ch = j; break; }
                j -= f;
            }
            return (unsigned int)(qt | (ch << 6) | (b << 8));
        };
        // remainder of length v (1..15), copy i in [0,16)
        auto remItem = [](int v, int i) -> unsigned int {
            int rep = i >> 2, b = i & 3;
            int qt = rep * 16 + v - 1, ch = rep;
            return (unsigned int)(qt | (ch << 6) | (b << 8));
        };
        if (bin < 128) {
            it[0] = fullItem(2 * bin);
            it[1] = fullItem(2 * bin + 1);
        } else if (bin < 240) {
            int t2 = bin - 128, v = 2 + (t2 >> 4), i = t2 & 15;
            it[0] = fullItem(256 + t2);
            it[1] = remItem(v, i);
            it[2] = remItem(17 - v, i);
        } else {
            int t2 = bin - 240;
            it[0] = fullItem(368 + 2 * t2);
            it[1] = fullItem(369 + 2 * t2);
            it[2] = remItem(1, t2);
        }
        for (int z = 0; z < 4; ++z) sched[z * 256 + bin] = it[z];
    }
}

// ---------------- QKV projection (R7 structure — async bf16 W staging) ----------------
__global__ __launch_bounds__(256, 3) void proj_kernel(
    const float* __restrict__ x, const unsigned short* __restrict__ wb,
    unsigned short* __restrict__ qb, unsigned short* __restrict__ kb,
    unsigned short* __restrict__ vbT)
{
    __shared__ __align__(16) unsigned short xs[2][64][64];
    __shared__ __align__(16) unsigned short wsm[2][128][64];

    const int gy = blockIdx.y;
    const unsigned short* wg = wb + (size_t)gy * Hn * En;

    const int m0 = blockIdx.x * 64;
    const int tid = threadIdx.x;
    const int lane = tid & 63, wave = tid >> 6;
    const int l15 = lane & 15, quad = lane >> 4;
    const int wm = (wave & 1) * 32;
    const int wn = (wave >> 1) * 64;

    f32x4 acc[2][4] = {};
    float4 xp[4];

    auto loadx = [&](int kc) {
        for (int p4 = 0; p4 < 4; ++p4) {
            int i = p4 * 256 + tid, row = i >> 4, c4 = (i & 15) * 4;
            xp[p4] = *(const float4*)&x[(size_t)(m0 + row) * En + kc * 64 + c4];
        }
    };
    auto writex = [&](int c) {
        for (int p4 = 0; p4 < 4; ++p4) {
            int i = p4 * 256 + tid, row = i >> 4, hc = i & 15;
            uint2 w2 = { pk2(xp[p4].x, xp[p4].y), pk2(xp[p4].z, xp[p4].w) };
            *(uint2*)((char*)&xs[c][0][0] + row * 128 + (((hc >> 1) ^ (row & 7)) << 4) + ((hc & 1) << 3)) = w2;
        }
    };
    auto issueW = [&](int kc, int c) {
        for (int j = 0; j < 4; ++j) {
            int seg = (wave * 4 + j) * 1024;
            int d = seg + (lane << 4);
            int row = d >> 7, chp = (d >> 4) & 7;
            gld16(wg + (size_t)row * En + kc * 64 + ((chp ^ (row & 7)) << 3),
                  (unsigned short*)((char*)&wsm[c][0][0] + seg));
        }
    };

    loadx(0);
    issueW(0, 0);
    writex(0);
    loadx(1);

    for (int kc = 0; kc < En / 64; ++kc) {
        const int c = kc & 1;
        __syncthreads();
        if (kc + 1 < En / 64) {
            issueW(kc + 1, c ^ 1);
            writex(c ^ 1);
            int kn = (kc + 2 < En / 64) ? kc + 2 : En / 64 - 1;
            loadx(kn);
        }
        bf16x8 xf[2][2], wf[4][2];
        for (int i = 0; i < 2; ++i)
            for (int kk = 0; kk < 2; ++kk) {
                int row = wm + i * 16 + l15;
                int chn = (kk * 4 + quad) ^ (row & 7);
                xf[i][kk] = *(const bf16x8*)((char*)&xs[c][0][0] + row * 128 + (chn << 4));
            }
        for (int j = 0; j < 4; ++j)
            for (int kk = 0; kk < 2; ++kk) {
                int row = wn + j * 16 + l15;
                int chn = (kk * 4 + quad) ^ (row & 7);
                wf[j][kk] = *(const bf16x8*)((char*)&wsm[c][0][0] + row * 128 + (chn << 4));
            }
        if (gy != 2) {
            for (int kk = 0; kk < 2; ++kk)
                for (int i = 0; i < 2; ++i)
                    for (int j = 0; j < 4; ++j)
                        acc[i][j] = MFMA16(xf[i][kk], wf[j][kk], acc[i][j]);
        } else {
            for (int kk = 0; kk < 2; ++kk)
                for (int i = 0; i < 2; ++i)
                    for (int j = 0; j < 4; ++j)
                        acc[i][j] = MFMA16(wf[j][kk], xf[i][kk], acc[i][j]);
        }
    }

    if (gy != 2) {
        unsigned short* ob = (gy == 0) ? qb : kb;
        const float osc = (gy == 0) ? CSCALE : 1.0f;
        for (int i = 0; i < 2; ++i) {
            int rowb = m0 + wm + i * 16 + quad * 4;
            for (int j = 0; j < 4; ++j) {
                int col = wn + j * 16 + l15;
                for (int r = 0; r < 4; ++r)
                    ob[(size_t)(rowb + r) * Hn + col] = f2bf(acc[i][j][r] * osc);
            }
        }
    } else {
        for (int j = 0; j < 4; ++j) {
            int hb = wn + j * 16 + quad * 4;
            for (int i = 0; i < 2; ++i) {
                int sp = m0 + wm + i * 16 + l15;
                int bb = sp >> 12, ss = sp & 4095;
                for (int r = 0; r < 4; ++r)
                    vbT[((size_t)(bb * 128 + hb + r)) * Sn + ss] = f2bf(acc[i][j][r]);
            }
        }
    }
}

// ---------------- attention: static balanced schedule (1024 blocks, table-driven) --------
// Block s runs item sched[s] (or no-ops). Body is byte-identical to the verified
// 58 µs kernel; only the (qt,ch,b) source changed from blockIdx to the table.
// Chunk = up to 16 BK=64 k-tiles. All waves share one K/V LDS tile.
// Per-lane online softmax (S^T = K Q^T: q on lane&15). Partials to ws when nch>1.
__global__ __launch_bounds__(256, 3) void attn_kernel(
    const unsigned short* __restrict__ qb, const unsigned short* __restrict__ kb,
    const unsigned short* __restrict__ vbT, float* __restrict__ out,
    float* __restrict__ part, const unsigned int* __restrict__ sched)
{
    __shared__ unsigned short ks[64][132];    // K tile [key][h]
    __shared__ unsigned short vt[128][68];    // V^T [h][key]
    __shared__ unsigned short ps[4][16][72];  // per-wave P strip [q][key]

    const unsigned int wi = sched[blockIdx.x];
    if (wi == 0xFFFFu) return;
    const int qt = (int)(wi & 63u);
    const int ch = (int)((wi >> 6) & 3u);
    const int b  = (int)((wi >> 8) & 3u);
    const int T  = qt + 1;                    // total k-tiles for this q-tile
    const int nch = (T + 15) >> 4;
    const int t0 = ch * 16;
    const int nloc = min(16, T - t0);
    const int q0 = qt * 64;

    const int tid = threadIdx.x;
    const int lane = tid & 63, wave = tid >> 6;
    const int l15 = lane & 15, quad = lane >> 4;

    const unsigned short* qg = qb + (size_t)(b * Sn + q0) * Hn;
    bf16x8 qf[4];
    for (int f = 0; f < 4; ++f)
        qf[f] = *(const bf16x8*)&qg[(wave * 16 + l15) * Hn + f * 32 + quad * 8];

    f32x4 o[8] = {};             // O^T: h = t*16+quad*4+r, q = l15 (this wave's row group)
    float m_r = -INFINITY, l_r = 0.f;

    const unsigned short* kg = kb + (size_t)b * Sn * Hn;
    const unsigned short* vg = vbT + (size_t)b * 128 * Sn;
    unsigned short* psrow = &ps[wave][l15][0];

    bf16x8 kreg[4], vreg[4];
    auto loadKV = [&](int gt) {
        int kt0 = gt * 64;
        for (int p4 = 0; p4 < 4; ++p4) {
            int i = p4 * 256 + tid;
            kreg[p4] = *(const bf16x8*)&kg[(size_t)(kt0 + (i >> 4)) * Hn + (i & 15) * 8];
            vreg[p4] = *(const bf16x8*)&vg[(size_t)(i >> 3) * Sn + kt0 + (i & 7) * 8];
        }
    };

    loadKV(t0);
    for (int tl = 0; tl < nloc; ++tl) {
        const int gt = t0 + tl;
        for (int p4 = 0; p4 < 4; ++p4) {
            int i = p4 * 256 + tid;
            *(bf16x8*)&ks[i >> 4][(i & 15) * 8] = kreg[p4];
            *(bf16x8*)&vt[i >> 3][(i & 7) * 8] = vreg[p4];
        }
        __syncthreads();
        if (tl + 1 < nloc) loadKV(gt + 1);

        // S^T: A = K (m=key), B = Q (n=q). u[nt][r]: key = gt*64+nt*16+quad*4+r, q = l15
        float u[4][4];
        for (int nt = 0; nt < 4; ++nt) {
            f32x4 s = {};
            for (int kk = 0; kk < 4; ++kk) {
                bf16x8 kf = *(const bf16x8*)&ks[nt * 16 + l15][kk * 32 + quad * 8];
                s = MFMA16(kf, qf[kk], s);
            }
            for (int r = 0; r < 4; ++r) u[nt][r] = s[r];
        }
        if (gt == qt) {   // only the last tile intersects the diagonal
            int qq = wave * 16 + l15;
            for (int nt = 0; nt < 4; ++nt)
                for (int r = 0; r < 4; ++r)
                    if (nt * 16 + quad * 4 + r > qq) u[nt][r] = -INFINITY;
        }
        // per-lane online softmax (log2 domain; CSCALE folded into q at projection)
        float mx = -INFINITY;
        for (int nt = 0; nt < 4; ++nt)
            for (int r = 0; r < 4; ++r) mx = fmaxf(mx, u[nt][r]);
        mx = fmaxf(mx, __shfl_xor(mx, 16));
        mx = fmaxf(mx, __shfl_xor(mx, 32));
        float mn = fmaxf(m_r, mx);
        float alpha = exp2f(m_r - mn);
        m_r = mn;
        float sum = 0.f;
        for (int nt = 0; nt < 4; ++nt)
            for (int r = 0; r < 4; ++r) {
                float pv = exp2f(u[nt][r] - mn);
                u[nt][r] = pv;
                sum += pv;
            }
        sum += __shfl_xor(sum, 16);
        sum += __shfl_xor(sum, 32);
        l_r = l_r * alpha + sum;

        // P -> LDS [q][key] (same-wave strip; no barrier needed)
        for (int nt = 0; nt < 4; ++nt) {
            uint2 w2 = { pk2(u[nt][0], u[nt][1]), pk2(u[nt][2], u[nt][3]) };
            *(uint2*)&psrow[nt * 16 + quad * 4] = w2;
        }
        for (int t = 0; t < 8; ++t) o[t] *= alpha;

        // O^T += V^T P^T
        for (int k2 = 0; k2 < 2; ++k2) {
            bf16x8 pf = *(const bf16x8*)&psrow[k2 * 32 + quad * 8];
            for (int t = 0; t < 8; ++t) {
                bf16x8 vf = *(const bf16x8*)&vt[t * 16 + l15][k2 * 32 + quad * 8];
                o[t] = MFMA16(vf, pf, o[t]);
            }
        }
        __syncthreads();   // protect ks/vt before next iteration's writes
    }

    if (nch == 1) {
        float inv = 1.0f / l_r;
        float* og = out + (size_t)(b * Sn + q0 + wave * 16 + l15) * Hn;
        for (int t = 0; t < 8; ++t) {
            float4 st = { o[t][0] * inv, o[t][1] * inv, o[t][2] * inv, o[t][3] * inv };
            *(float4*)&og[t * 16 + quad * 4] = st;
        }
    } else {
        float* P = part + (size_t)(b * SB + sb64(qt) + ch) * SLOT_F;
        int q = wave * 16 + l15;
        for (int t = 0; t < 8; ++t) {
            float4 st = { o[t][0], o[t][1], o[t][2], o[t][3] };
            *(float4*)&P[q * 128 + t * 16 + quad * 4] = st;
        }
        if (quad == 0) {
            P[8192 + q] = m_r;
            P[8256 + q] = l_r;
        }
    }
}

// ---------------- merge partials for qt >= 16 ----------------
// grid (48, B), 256 thr: q = tid>>2 (64 rows), h0 = (tid&3)*32 (32 h each)
__global__ __launch_bounds__(256) void merge_kernel(
    const float* __restrict__ part, float* __restrict__ out)
{
    const int qt = 16 + blockIdx.x;
    const int b = blockIdx.y;
    const int nch = (qt + 16) >> 4;
    const float* P0 = part + (size_t)(b * SB + sb64(qt)) * SLOT_F;
    const int q = threadIdx.x >> 2;
    const int h0 = (threadIdx.x & 3) * 32;

    float m[4], w[4];
    float M = -INFINITY;
    for (int c = 0; c < nch; ++c) {
        m[c] = P0[(size_t)c * SLOT_F + 8192 + q];
        M = fmaxf(M, m[c]);
    }
    float L = 0.f;
    for (int c = 0; c < nch; ++c) {
        w[c] = exp2f(m[c] - M);
        L += w[c] * P0[(size_t)c * SLOT_F + 8256 + q];
    }
    float inv = 1.0f / L;

    float acc[32] = {};
    for (int c = 0; c < nch; ++c) {
        const float* Pq = P0 + (size_t)c * SLOT_F + q * 128 + h0;
        for (int j = 0; j < 8; ++j) {
            float4 v = *(const float4*)&Pq[j * 4];
            acc[j * 4 + 0] += w[c] * v.x;
            acc[j * 4 + 1] += w[c] * v.y;
            acc[j * 4 + 2] += w[c] * v.z;
            acc[j * 4 + 3] += w[c] * v.w;
        }
    }
    float* og = out + (size_t)(b * Sn + qt * 64 + q) * Hn + h0;
    for (int j = 0; j < 8; ++j) {
        float4 st = { acc[j * 4 + 0] * inv, acc[j * 4 + 1] * inv,
                      acc[j * 4 + 2] * inv, acc[j * 4 + 3] * inv };
        *(float4*)&og[j * 4] = st;
    }
}

extern "C" void kernel_launch(void* const* d_in, const int* in_sizes, int n_in,
                              void* d_out, int out_size, void* d_ws, size_t ws_size,
                              hipStream_t stream)
{
    const float* x  = (const float*)d_in[0];
    const float* Wk = (const float*)d_in[1];
    const float* Wq = (const float*)d_in[2];
    const float* Wv = (const float*)d_in[3];
    float* out = (float*)d_out;

    unsigned short* qbuf  = (unsigned short*)d_ws;                  // 4 MB (pre-scaled)
    unsigned short* kbuf  = qbuf + (size_t)Bn * Sn * Hn;            // 4 MB
    unsigned short* vbufT = kbuf + (size_t)Bn * Sn * Hn;            // 4 MB, [b][h][s]
    unsigned short* wb    = vbufT + (size_t)Bn * Sn * Hn;           // 0.75 MB bf16 W
    float* part = (float*)(wb + (size_t)3 * Hn * En);               // 21.3 MB partials
    // schedule table lives in part's qt<16 slot region (partial writes start at
    // float offset 16*SLOT_F = 133120; table uses [0..1024))
    unsigned int* sched = (unsigned int*)part;

    prep_kernel<<<96, 256, 0, stream>>>(Wk, Wq, Wv, wb, sched);
    proj_kernel<<<dim3(Bn * Sn / 64, 3), 256, 0, stream>>>(x, wb, qbuf, kbuf, vbufT);
    attn_kernel<<<1024, 256, 0, stream>>>(qbuf, kbuf, vbufT, out, part, sched);
    merge_kernel<<<dim3(48, Bn), 256, 0, stream>>>(part, out);
}